// Round 1
// baseline (207.110 us; speedup 1.0000x reference)
//
#include <hip/hip_runtime.h>

#define B_ 4096
#define T_ 1024
#define H_ 15

// DPP helper. ctrl must be a compile-time constant.
// row_ror:n (ctrl 0x120+n): lane l reads lane (l-n)&15 within its 16-lane row.
// row_shr:n (ctrl 0x110+n): lane l reads lane l-n; lanes l<n get 0 (bound_ctrl).
template <int CTRL>
__device__ __forceinline__ float dpp_f(float v) {
  return __int_as_float(
      __builtin_amdgcn_update_dpp(0, __float_as_int(v), CTRL, 0xF, 0xF, true));
}

__global__ __launch_bounds__(256) void rnn_tanh_kernel(
    const float* __restrict__ x, const float* __restrict__ w_ih,
    const float* __restrict__ w_hh, const float* __restrict__ b_ih,
    const float* __restrict__ b_hh, const float* __restrict__ w_lin,
    const float* __restrict__ b_lin, float* __restrict__ out) {
  const int tid = threadIdx.x;
  const int lane = tid & 15;               // hidden row this lane owns (15 = pad)
  const int grp = tid >> 4;                // batch-group within block (0..15)
  const int b = blockIdx.x * 16 + grp;     // batch index

  // Per-lane recurrent weights, permuted for the rotation schedule:
  // at rotation n, this lane sees h[(lane-n)&15], so it needs W[lane][(lane-n)&15].
  // Pad row 15 / col 15 with zeros so the pad lane stays exactly 0.
  float wr[16];
#pragma unroll
  for (int n = 0; n < 16; ++n) {
    const int c = (lane - n) & 15;
    wr[n] = (lane < H_ && c < H_) ? w_hh[lane * H_ + c] : 0.0f;
  }
  const float wih  = (lane < H_) ? w_ih[lane] : 0.0f;
  const float bias = (lane < H_) ? (b_ih[lane] + b_hh[lane]) : 0.0f;
  const float wlin = (lane < H_) ? w_lin[lane] : 0.0f;
  const float blin = b_lin[0];

  const float* xb = x + (size_t)b * T_;
  float* ob = out + (size_t)b * T_;

  float h = 0.0f;  // h[lane], lane 15 stays exactly 0 (tanh(0)=0 with zero weights)

  auto step = [&](float xt) -> float {
    // preactivation: a[l] = x_t*w_ih[l] + b_ih[l] + b_hh[l] + sum_j W[l][j]*h[j]
    float a0 = fmaf(xt, wih, bias);
    a0 = fmaf(wr[0], h, a0);
    float a1 = wr[1] * dpp_f<0x121>(h);
    float a2 = wr[2] * dpp_f<0x122>(h);
    float a3 = wr[3] * dpp_f<0x123>(h);
    a0 = fmaf(wr[4],  dpp_f<0x124>(h), a0);
    a1 = fmaf(wr[5],  dpp_f<0x125>(h), a1);
    a2 = fmaf(wr[6],  dpp_f<0x126>(h), a2);
    a3 = fmaf(wr[7],  dpp_f<0x127>(h), a3);
    a0 = fmaf(wr[8],  dpp_f<0x128>(h), a0);
    a1 = fmaf(wr[9],  dpp_f<0x129>(h), a1);
    a2 = fmaf(wr[10], dpp_f<0x12a>(h), a2);
    a3 = fmaf(wr[11], dpp_f<0x12b>(h), a3);
    a0 = fmaf(wr[12], dpp_f<0x12c>(h), a0);
    a1 = fmaf(wr[13], dpp_f<0x12d>(h), a1);
    a2 = fmaf(wr[14], dpp_f<0x12e>(h), a2);
    a3 = fmaf(wr[15], dpp_f<0x12f>(h), a3);
    const float a = (a0 + a1) + (a2 + a3);
    // tanh(a) = 1 - 2/(exp(2a)+1); saturates correctly via inf/rcp(inf)=0
    const float e = __expf(a + a);
    h = fmaf(-2.0f, __builtin_amdgcn_rcpf(e + 1.0f), 1.0f);
    // output head: sum_l h[l]*w_lin[l] + b_lin, reduced across the 16-lane row;
    // full sum lands in lane 15 via row_shr butterfly.
    float p = h * wlin;
    p += dpp_f<0x111>(p);
    p += dpp_f<0x112>(p);
    p += dpp_f<0x114>(p);
    p += dpp_f<0x118>(p);
    return p + blin;
  };

  float4 xv = *(const float4*)xb;  // current 4 timesteps of x for this batch
  for (int t = 0; t < T_; t += 4) {
    const int tn = (t + 4 < T_) ? (t + 4) : 0;  // clamp to stay in-bounds
    const float4 xn = *(const float4*)(xb + tn);  // prefetch next chunk
    const float o0 = step(xv.x);
    const float o1 = step(xv.y);
    const float o2 = step(xv.z);
    const float o3 = step(xv.w);
    if (lane == 15) *(float4*)(ob + t) = make_float4(o0, o1, o2, o3);
    xv = xn;
  }
}

extern "C" void kernel_launch(void* const* d_in, const int* in_sizes, int n_in,
                              void* d_out, int out_size, void* d_ws, size_t ws_size,
                              hipStream_t stream) {
  (void)in_sizes; (void)n_in; (void)out_size; (void)d_ws; (void)ws_size;
  rnn_tanh_kernel<<<B_ / 16, 256, 0, stream>>>(
      (const float*)d_in[0], (const float*)d_in[1], (const float*)d_in[2],
      (const float*)d_in[3], (const float*)d_in[4], (const float*)d_in[5],
      (const float*)d_in[6], (float*)d_out);
}